// Round 3
// baseline (430.201 us; speedup 1.0000x reference)
//
#include <hip/hip_runtime.h>
#include <hip/hip_bf16.h>
#include <cstdint>
#include <cstddef>

// ---------------------------------------------------------------------------
// E3nnMLPNorm: only the l=1 (d=3) irrep path is nonzero.
// pipeline: layer0 (K=2) -> [gemm -> colsumsq -> bn+gate] x5 -> final dot
// Precision scheme: activations & weights stored as bf16 PAIRS (hi + lo),
// GEMM = 3 bf16 MFMA products (lo*hi + hi*lo + hi*hi) into one f32 acc.
// Combined storage rel err ~2^-18 (vs fp16 single 2^-12 which failed at 0.11).
// ---------------------------------------------------------------------------

typedef short    s16x8 __attribute__((ext_vector_type(8)));
typedef float    f32x4 __attribute__((ext_vector_type(4)));

#define PLANE 1048576   // 1024*1024 elements per plane

__device__ __forceinline__ unsigned short f2bf(float f) {
  unsigned u = __builtin_bit_cast(unsigned, f);
  u += 0x7FFFu + ((u >> 16) & 1u);              // round-to-nearest-even
  return (unsigned short)(u >> 16);
}
__device__ __forceinline__ float bf2f(unsigned short h) {
  return __builtin_bit_cast(float, (unsigned)h << 16);
}

__device__ __forceinline__ void load_lds16(const void* g, void* l) {
  __builtin_amdgcn_global_load_lds(
      (const __attribute__((address_space(1))) unsigned int*)g,
      (__attribute__((address_space(3))) unsigned int*)l,
      16, 0, 0);
}

// ---- W[b,0] (f32 [u][v]) -> Wt (bf16 hi/lo [v][u]) with 1/32 folded in -----
__global__ void convert_w(const float* __restrict__ W,
                          unsigned short* __restrict__ Wh,
                          unsigned short* __restrict__ Wl) {
  __shared__ float t[64][65];
  const int u0 = blockIdx.x * 64, v0 = blockIdx.y * 64;
  const float* Wb = W + (size_t)blockIdx.z * 4194304;   // [5][4][1024][1024], irrep 0
  unsigned short* Whb = Wh + (size_t)blockIdx.z * PLANE;
  unsigned short* Wlb = Wl + (size_t)blockIdx.z * PLANE;
  const int c = threadIdx.x & 63, r4 = threadIdx.x >> 6;
#pragma unroll
  for (int i = 0; i < 16; ++i) {
    const int r = i * 4 + r4;
    t[r][c] = Wb[(size_t)(u0 + r) * 1024 + v0 + c];
  }
  __syncthreads();
#pragma unroll
  for (int i = 0; i < 16; ++i) {
    const int r = i * 4 + r4;   // local v index
    const float w = t[c][r] * 0.03125f;      // exact pow2 scale
    const unsigned short hi = f2bf(w);
    const size_t idx = (size_t)(v0 + r) * 1024 + u0 + c;
    Whb[idx] = hi;
    Wlb[idx] = f2bf(w - bf2f(hi));
  }
}

// ---- layer0: pre[i][b][v] = (x[b,0,i]*w1[0,v] + x[b,1,i]*w1[1,v]) / sqrt(2) -
__global__ void layer0(const float* __restrict__ x, const float* __restrict__ w1,
                       float* __restrict__ pre) {
  const int gid = blockIdx.x * 256 + threadIdx.x;   // b*1024 + v
  const int v = gid & 1023, b = gid >> 10;
  const float a0 = w1[v], a1 = w1[1024 + v];
  const float* xb = x + b * 6;                      // x flat [B][2][3]
  const float inv = 0.70710678118654752f;
#pragma unroll
  for (int i = 0; i < 3; ++i)
    pre[(size_t)i * PLANE + gid] = (xb[i] * a0 + xb[3 + i] * a1) * inv;
}

// ---- column sum of squares over all 3072 rows -> var[v] (atomic) ------------
__global__ void colsumsq(const float* __restrict__ pre, float* __restrict__ var) {
  const int col = blockIdx.y * 256 + threadIdx.x;
  const int r0 = blockIdx.x * 128;                  // 24 row-chunks of 128
  float s = 0.f;
#pragma unroll 4
  for (int r = 0; r < 128; ++r) {
    const float v = pre[(size_t)(r0 + r) * 1024 + col];
    s += v * v;
  }
  atomicAdd(&var[col], s);
}

// ---- batchnorm scale + norm-gated sigmoid, write bf16 hi/lo act -------------
__global__ void act_kernel(const float* __restrict__ pre, const float* __restrict__ var,
                           const float* __restrict__ bnw,
                           unsigned short* __restrict__ ah,
                           unsigned short* __restrict__ al) {
  const int gid = blockIdx.x * 256 + threadIdx.x;   // b*1024 + v
  const int v = gid & 1023;
  const float s = bnw[v] / sqrtf(var[v] * (1.0f / 3072.0f) + 1e-5f);
  const float f0 = pre[gid] * s;
  const float f1 = pre[gid + PLANE] * s;
  const float f2 = pre[gid + 2 * PLANE] * s;
  const float n = sqrtf(f0 * f0 + f1 * f1 + f2 * f2 + 1e-8f);
  const float g = 1.0f / ((1.0f + expf(-n)) * n);   // sigmoid(n)/n
  const float o0 = f0 * g, o1 = f1 * g, o2 = f2 * g;
  const unsigned short h0 = f2bf(o0), h1 = f2bf(o1), h2 = f2bf(o2);
  ah[gid]             = h0;  al[gid]             = f2bf(o0 - bf2f(h0));
  ah[gid + PLANE]     = h1;  al[gid + PLANE]     = f2bf(o1 - bf2f(h1));
  ah[gid + 2 * PLANE] = h2;  al[gid + 2 * PLANE] = f2bf(o2 - bf2f(h2));
}

// ---- bf16-pair MFMA GEMM: C[3072][1024] = (Ah+Al) * (Bh+Bl)^T ---------------
// 128x128 tile, 4 waves (2x2), each wave 64x64 = 4x4 frags of 16x16x32.
// LDS [kc][row][8]: linear in global_load_lds lane order, conflict-free reads.
__global__ __launch_bounds__(256) void gemm_bf16pair(
    const unsigned short* __restrict__ Ah, const unsigned short* __restrict__ Al,
    const unsigned short* __restrict__ Bh, const unsigned short* __restrict__ Bl,
    float* __restrict__ C) {
  __shared__ unsigned short sAh[4][128][8];
  __shared__ unsigned short sAl[4][128][8];
  __shared__ unsigned short sBh[4][128][8];
  __shared__ unsigned short sBl[4][128][8];
  const int tid = threadIdx.x;
  const int bm0 = blockIdx.x * 128;
  const int bn0 = blockIdx.y * 128;
  const int lane = tid & 63;
  const int wave = tid >> 6;
  const int wm = (wave >> 1) * 64;
  const int wn = (wave & 1) * 64;
  const int rsel = lane & 15;
  const int kcsel = lane >> 4;

  f32x4 acc[4][4] = {};

  // staging: thread covers (row = tid&127, 16B-chunk = tid>>7) of each K-tile
  const size_t rowoff = ((size_t)(tid & 127) << 11) + ((tid >> 7) << 4);
  const char* aHs = (const char*)Ah + ((size_t)bm0 << 11) + rowoff;
  const char* aLs = (const char*)Al + ((size_t)bm0 << 11) + rowoff;
  const char* bHs = (const char*)Bh + ((size_t)bn0 << 11) + rowoff;
  const char* bLs = (const char*)Bl + ((size_t)bn0 << 11) + rowoff;
  char* aHl = (char*)&sAh[0][0][0] + (wave << 10);   // wave-uniform LDS bases
  char* aLl = (char*)&sAl[0][0][0] + (wave << 10);
  char* bHl = (char*)&sBh[0][0][0] + (wave << 10);
  char* bLl = (char*)&sBl[0][0][0] + (wave << 10);

  for (int kt = 0; kt < 32; ++kt) {
    const int kb = kt << 6;                        // byte offset along K
    load_lds16(aHs + kb,      aHl);
    load_lds16(aHs + kb + 32, aHl + 4096);
    load_lds16(aLs + kb,      aLl);
    load_lds16(aLs + kb + 32, aLl + 4096);
    load_lds16(bHs + kb,      bHl);
    load_lds16(bHs + kb + 32, bHl + 4096);
    load_lds16(bLs + kb,      bLl);
    load_lds16(bLs + kb + 32, bLl + 4096);
    __syncthreads();                               // drains vmcnt before barrier

    s16x8 ah[4], al[4], bh[4], bl[4];
#pragma unroll
    for (int m = 0; m < 4; ++m) {
      ah[m] = *(const s16x8*)&sAh[kcsel][wm + m * 16 + rsel][0];
      al[m] = *(const s16x8*)&sAl[kcsel][wm + m * 16 + rsel][0];
    }
#pragma unroll
    for (int n = 0; n < 4; ++n) {
      bh[n] = *(const s16x8*)&sBh[kcsel][wn + n * 16 + rsel][0];
      bl[n] = *(const s16x8*)&sBl[kcsel][wn + n * 16 + rsel][0];
    }
#pragma unroll
    for (int m = 0; m < 4; ++m)
#pragma unroll
      for (int n = 0; n < 4; ++n) {
        acc[m][n] = __builtin_amdgcn_mfma_f32_16x16x32_bf16(al[m], bh[n], acc[m][n], 0, 0, 0);
        acc[m][n] = __builtin_amdgcn_mfma_f32_16x16x32_bf16(ah[m], bl[n], acc[m][n], 0, 0, 0);
        acc[m][n] = __builtin_amdgcn_mfma_f32_16x16x32_bf16(ah[m], bh[n], acc[m][n], 0, 0, 0);
      }
    __syncthreads();                               // protect LDS before next stage
  }

  // epilogue: D row = (lane>>4)*4 + j, col = lane&15  [m89-verified layout]
  const int r0 = bm0 + wm + (kcsel << 2);
  const int c0 = bn0 + wn + rsel;
#pragma unroll
  for (int m = 0; m < 4; ++m)
#pragma unroll
    for (int n = 0; n < 4; ++n)
#pragma unroll
      for (int j = 0; j < 4; ++j)
        C[(size_t)(r0 + m * 16 + j) * 1024 + c0 + n * 16] = acc[m][n][j];
}

// ---- final: out[b,i] = (1/32) * sum_v act[i][b][v] * wout[v] ----------------
__global__ void final_kernel(const unsigned short* __restrict__ ah,
                             const unsigned short* __restrict__ al,
                             const float* __restrict__ wout, float* __restrict__ out) {
  const int b = blockIdx.x, tid = threadIdx.x;
  __shared__ float red[3][4];
  float s[3] = {0.f, 0.f, 0.f};
  for (int v = tid; v < 1024; v += 256) {
    const float w = wout[v];
    const size_t base = (size_t)b * 1024 + v;
    s[0] += (bf2f(ah[base])             + bf2f(al[base]))             * w;
    s[1] += (bf2f(ah[base + PLANE])     + bf2f(al[base + PLANE]))     * w;
    s[2] += (bf2f(ah[base + 2 * PLANE]) + bf2f(al[base + 2 * PLANE])) * w;
  }
#pragma unroll
  for (int i = 0; i < 3; ++i)
    for (int o = 32; o >= 1; o >>= 1) s[i] += __shfl_down(s[i], o);
  if ((tid & 63) == 0)
#pragma unroll
    for (int i = 0; i < 3; ++i) red[i][tid >> 6] = s[i];
  __syncthreads();
  if (tid < 3) {
    const float t = red[tid][0] + red[tid][1] + red[tid][2] + red[tid][3];
    out[b * 3 + tid] = t * 0.03125f;
  }
}

extern "C" void kernel_launch(void* const* d_in, const int* in_sizes, int n_in,
                              void* d_out, int out_size, void* d_ws, size_t ws_size,
                              hipStream_t stream) {
  const float* x    = (const float*)d_in[0];
  const float* w1   = (const float*)d_in[1];
  const float* W    = (const float*)d_in[2];
  const float* bnw  = (const float*)d_in[3];
  const float* wout = (const float*)d_in[4];
  float* out = (float*)d_out;

  char* ws = (char*)d_ws;
  float*          var = (float*)ws;                         // 6*1024 f32 (32 KB resv)
  float*          pre = (float*)(ws + 32768);               // 3072*1024 f32 (12 MB)
  unsigned short* ah  = (unsigned short*)(ws + 12615680);   // 3*1M bf16 (6 MB)
  unsigned short* al  = (unsigned short*)(ws + 18907136);   // 3*1M bf16 (6 MB)
  unsigned short* wh  = (unsigned short*)(ws + 25198592);   // 5*1M bf16 (10 MB)
  unsigned short* wl  = (unsigned short*)(ws + 35684352);   // 5*1M bf16 (10 MB)

  hipMemsetAsync(var, 0, 6 * 1024 * sizeof(float), stream);
  convert_w<<<dim3(16, 16, 5), 256, 0, stream>>>(W, wh, wl);
  layer0<<<4096, 256, 0, stream>>>(x, w1, pre);
  colsumsq<<<dim3(24, 4), 256, 0, stream>>>(pre, var);
  act_kernel<<<4096, 256, 0, stream>>>(pre, var, bnw, ah, al);
  for (int b = 0; b < 5; ++b) {
    gemm_bf16pair<<<dim3(24, 8), 256, 0, stream>>>(
        ah, al, wh + (size_t)b * PLANE, wl + (size_t)b * PLANE, pre);
    colsumsq<<<dim3(24, 4), 256, 0, stream>>>(pre, var + (b + 1) * 1024);
    act_kernel<<<4096, 256, 0, stream>>>(pre, var + (b + 1) * 1024,
                                         bnw + (size_t)(b + 1) * 4096, ah, al);
  }
  final_kernel<<<1024, 256, 0, stream>>>(ah, al, wout, out);
}

// Round 4
// 294.113 us; speedup vs baseline: 1.4627x; 1.4627x over previous
//
#include <hip/hip_runtime.h>
#include <hip/hip_bf16.h>
#include <cstdint>
#include <cstddef>

// ---------------------------------------------------------------------------
// E3nnMLPNorm: only the l=1 (d=3) irrep path is nonzero.
// layer0 (K=2) -> [gemm(+fused colsumsq) -> bn+gate] x5 -> final dot
// Precision: bf16 hi+lo pairs, 3 bf16 MFMA per fragment into f32 acc.
// GEMM: 128x128 tile, 4 waves, 2-phase double-buffered LDS pipeline with
// counted vmcnt(8) (T3+T4 minimal recipe) — latency hiding without TLP.
// ---------------------------------------------------------------------------

typedef short    s16x8 __attribute__((ext_vector_type(8)));
typedef float    f32x4 __attribute__((ext_vector_type(4)));

#define PLANE 1048576   // 1024*1024 elements per plane

__device__ __forceinline__ unsigned short f2bf(float f) {
  unsigned u = __builtin_bit_cast(unsigned, f);
  u += 0x7FFFu + ((u >> 16) & 1u);              // round-to-nearest-even
  return (unsigned short)(u >> 16);
}
__device__ __forceinline__ float bf2f(unsigned short h) {
  return __builtin_bit_cast(float, (unsigned)h << 16);
}

__device__ __forceinline__ void load_lds16(const void* g, void* l) {
  __builtin_amdgcn_global_load_lds(
      (const __attribute__((address_space(1))) unsigned int*)g,
      (__attribute__((address_space(3))) unsigned int*)l,
      16, 0, 0);
}

// ---- W[b,0] (f32 [u][v]) -> bf16 hi/lo [v][u] with 1/32 folded in ----------
__global__ void convert_w(const float* __restrict__ W,
                          unsigned short* __restrict__ Wh,
                          unsigned short* __restrict__ Wl) {
  __shared__ float t[64][65];
  const int u0 = blockIdx.x * 64, v0 = blockIdx.y * 64;
  const float* Wb = W + (size_t)blockIdx.z * 4194304;   // [5][4][1024][1024], irrep 0
  unsigned short* Whb = Wh + (size_t)blockIdx.z * PLANE;
  unsigned short* Wlb = Wl + (size_t)blockIdx.z * PLANE;
  const int c = threadIdx.x & 63, r4 = threadIdx.x >> 6;
#pragma unroll
  for (int i = 0; i < 16; ++i) {
    const int r = i * 4 + r4;
    t[r][c] = Wb[(size_t)(u0 + r) * 1024 + v0 + c];
  }
  __syncthreads();
#pragma unroll
  for (int i = 0; i < 16; ++i) {
    const int r = i * 4 + r4;   // local v index
    const float w = t[c][r] * 0.03125f;      // exact pow2 scale
    const unsigned short hi = f2bf(w);
    const size_t idx = (size_t)(v0 + r) * 1024 + u0 + c;
    Whb[idx] = hi;
    Wlb[idx] = f2bf(w - bf2f(hi));
  }
}

// ---- layer0: pre[i][b][v] = (x[b,0,i]*w1[0,v] + x[b,1,i]*w1[1,v]) / sqrt(2) -
__global__ void layer0(const float* __restrict__ x, const float* __restrict__ w1,
                       float* __restrict__ pre) {
  const int gid = blockIdx.x * 256 + threadIdx.x;   // b*1024 + v
  const int v = gid & 1023, b = gid >> 10;
  const float a0 = w1[v], a1 = w1[1024 + v];
  const float* xb = x + b * 6;                      // x flat [B][2][3]
  const float inv = 0.70710678118654752f;
#pragma unroll
  for (int i = 0; i < 3; ++i)
    pre[(size_t)i * PLANE + gid] = (xb[i] * a0 + xb[3 + i] * a1) * inv;
}

// ---- column sum of squares (layer0 only) -> var[v] (atomic) -----------------
__global__ void colsumsq(const float* __restrict__ pre, float* __restrict__ var) {
  const int col = blockIdx.y * 256 + threadIdx.x;
  const int r0 = blockIdx.x * 128;                  // 24 row-chunks of 128
  float s = 0.f;
#pragma unroll 4
  for (int r = 0; r < 128; ++r) {
    const float v = pre[(size_t)(r0 + r) * 1024 + col];
    s += v * v;
  }
  atomicAdd(&var[col], s);
}

// ---- batchnorm scale + norm-gated sigmoid, write bf16 hi/lo (x4 vector) -----
__global__ void act_kernel(const float* __restrict__ pre, const float* __restrict__ var,
                           const float* __restrict__ bnw,
                           unsigned short* __restrict__ ah,
                           unsigned short* __restrict__ al) {
  const int idx = (blockIdx.x * 256 + threadIdx.x) * 4;   // 262144 threads x4
  const int v = idx & 1023;
  const float4 p0 = *(const float4*)&pre[idx];
  const float4 p1 = *(const float4*)&pre[idx + PLANE];
  const float4 p2 = *(const float4*)&pre[idx + 2 * PLANE];
  const float a0[4] = {p0.x, p0.y, p0.z, p0.w};
  const float a1[4] = {p1.x, p1.y, p1.z, p1.w};
  const float a2[4] = {p2.x, p2.y, p2.z, p2.w};
  unsigned short H0[4], L0[4], H1[4], L1[4], H2[4], L2[4];
#pragma unroll
  for (int j = 0; j < 4; ++j) {
    const float s = bnw[v + j] / sqrtf(var[v + j] * (1.0f / 3072.0f) + 1e-5f);
    const float f0 = a0[j] * s, f1 = a1[j] * s, f2 = a2[j] * s;
    const float n = sqrtf(f0 * f0 + f1 * f1 + f2 * f2 + 1e-8f);
    const float g = 1.0f / ((1.0f + expf(-n)) * n);   // sigmoid(n)/n
    const float o0 = f0 * g, o1 = f1 * g, o2 = f2 * g;
    H0[j] = f2bf(o0); L0[j] = f2bf(o0 - bf2f(H0[j]));
    H1[j] = f2bf(o1); L1[j] = f2bf(o1 - bf2f(H1[j]));
    H2[j] = f2bf(o2); L2[j] = f2bf(o2 - bf2f(H2[j]));
  }
  *(ushort4*)&ah[idx]             = make_ushort4(H0[0], H0[1], H0[2], H0[3]);
  *(ushort4*)&al[idx]             = make_ushort4(L0[0], L0[1], L0[2], L0[3]);
  *(ushort4*)&ah[idx + PLANE]     = make_ushort4(H1[0], H1[1], H1[2], H1[3]);
  *(ushort4*)&al[idx + PLANE]     = make_ushort4(L1[0], L1[1], L1[2], L1[3]);
  *(ushort4*)&ah[idx + 2 * PLANE] = make_ushort4(H2[0], H2[1], H2[2], H2[3]);
  *(ushort4*)&al[idx + 2 * PLANE] = make_ushort4(L2[0], L2[1], L2[2], L2[3]);
}

// ---- bf16-pair MFMA GEMM + fused column-sumsq epilogue ----------------------
// C[3072][1024] = (Ah+Al) * (Bh+Bl)^T ; var[col] += sum_rows C^2
// 2-phase double-buffered pipeline, counted vmcnt(8), raw s_barrier.
__global__ __launch_bounds__(256) void gemm_fused(
    const unsigned short* __restrict__ Ah, const unsigned short* __restrict__ Al,
    const unsigned short* __restrict__ Bh, const unsigned short* __restrict__ Bl,
    float* __restrict__ C, float* __restrict__ var) {
  // [buf][mat: aH,aL,bH,bL][kc][row][8 halves]  = 64 KB
  __shared__ unsigned short lds[2][4][4][128][8];
  const int tid = threadIdx.x;
  const int bm0 = blockIdx.x * 128, bn0 = blockIdx.y * 128;
  const int lane = tid & 63, wave = tid >> 6;
  const int wm = (wave >> 1) * 64, wn = (wave & 1) * 64;
  const int rsel = lane & 15, kcsel = lane >> 4;

  f32x4 acc[4][4] = {};

  // global staging addresses: thread covers (row = tid&127, chunk = tid>>7)
  const size_t rowoff = ((size_t)(tid & 127) << 11) + ((tid >> 7) << 4);
  const char* g0 = (const char*)Ah + ((size_t)bm0 << 11) + rowoff;
  const char* g1 = (const char*)Al + ((size_t)bm0 << 11) + rowoff;
  const char* g2 = (const char*)Bh + ((size_t)bn0 << 11) + rowoff;
  const char* g3 = (const char*)Bl + ((size_t)bn0 << 11) + rowoff;

  auto stage = [&](int buf, int kt) {
    const int kb = kt << 6;                        // byte offset along K
    char* base = (char*)&lds[buf][0][0][0][0] + (wave << 10);  // wave-uniform
    load_lds16(g0 + kb, base);          load_lds16(g0 + kb + 32, base + 4096);
    load_lds16(g1 + kb, base + 8192);   load_lds16(g1 + kb + 32, base + 12288);
    load_lds16(g2 + kb, base + 16384);  load_lds16(g2 + kb + 32, base + 20480);
    load_lds16(g3 + kb, base + 24576);  load_lds16(g3 + kb + 32, base + 28672);
  };

  auto compute = [&](int buf) {
    s16x8 fah[4], fal[4], fbh[4], fbl[4];
#pragma unroll
    for (int m = 0; m < 4; ++m) {
      fah[m] = *(const s16x8*)&lds[buf][0][kcsel][wm + m * 16 + rsel][0];
      fal[m] = *(const s16x8*)&lds[buf][1][kcsel][wm + m * 16 + rsel][0];
    }
#pragma unroll
    for (int n = 0; n < 4; ++n) {
      fbh[n] = *(const s16x8*)&lds[buf][2][kcsel][wn + n * 16 + rsel][0];
      fbl[n] = *(const s16x8*)&lds[buf][3][kcsel][wn + n * 16 + rsel][0];
    }
#pragma unroll
    for (int m = 0; m < 4; ++m)
#pragma unroll
      for (int n = 0; n < 4; ++n) {
        acc[m][n] = __builtin_amdgcn_mfma_f32_16x16x32_bf16(fal[m], fbh[n], acc[m][n], 0, 0, 0);
        acc[m][n] = __builtin_amdgcn_mfma_f32_16x16x32_bf16(fah[m], fbl[n], acc[m][n], 0, 0, 0);
        acc[m][n] = __builtin_amdgcn_mfma_f32_16x16x32_bf16(fah[m], fbh[n], acc[m][n], 0, 0, 0);
      }
  };

  stage(0, 0);                                     // prologue
  for (int t = 0; t < 31; ++t) {
    stage((t + 1) & 1, t + 1);                     // prefetch next K-step
    __builtin_amdgcn_sched_barrier(0);
    asm volatile("s_waitcnt vmcnt(8)" ::: "memory");  // wait stage(t) only
    __builtin_amdgcn_sched_barrier(0);
    __builtin_amdgcn_s_barrier();
    compute(t & 1);
    __builtin_amdgcn_sched_barrier(0);
    __builtin_amdgcn_s_barrier();                  // protect buf before overwrite
  }
  __builtin_amdgcn_sched_barrier(0);
  asm volatile("s_waitcnt vmcnt(0)" ::: "memory");
  __builtin_amdgcn_sched_barrier(0);
  __builtin_amdgcn_s_barrier();
  compute(1);                                      // t=31

  // epilogue: store + fused per-column sum of squares
  // D row = (lane>>4)*4 + j, col = lane&15  [m89-verified layout]
  const int r0 = bm0 + wm + (kcsel << 2);
  const int c0 = bn0 + wn + rsel;
  float csq[4] = {0.f, 0.f, 0.f, 0.f};
#pragma unroll
  for (int m = 0; m < 4; ++m)
#pragma unroll
    for (int n = 0; n < 4; ++n)
#pragma unroll
      for (int j = 0; j < 4; ++j) {
        const float v = acc[m][n][j];
        C[(size_t)(r0 + m * 16 + j) * 1024 + c0 + n * 16] = v;
        csq[n] += v * v;
      }
  // reduce over kcsel lanes (rows within wave): lanes rsel, +16, +32, +48
#pragma unroll
  for (int n = 0; n < 4; ++n) {
    csq[n] += __shfl_xor(csq[n], 16);
    csq[n] += __shfl_xor(csq[n], 32);
  }
  if (kcsel == 0) {
#pragma unroll
    for (int n = 0; n < 4; ++n)
      atomicAdd(&var[c0 + n * 16], csq[n]);
  }
}

// ---- final: out[b,i] = (1/32) * sum_v act[i][b][v] * wout[v] ----------------
__global__ void final_kernel(const unsigned short* __restrict__ ah,
                             const unsigned short* __restrict__ al,
                             const float* __restrict__ wout, float* __restrict__ out) {
  const int b = blockIdx.x, tid = threadIdx.x;
  __shared__ float red[3][4];
  float s[3] = {0.f, 0.f, 0.f};
  for (int v = tid; v < 1024; v += 256) {
    const float w = wout[v];
    const size_t base = (size_t)b * 1024 + v;
    s[0] += (bf2f(ah[base])             + bf2f(al[base]))             * w;
    s[1] += (bf2f(ah[base + PLANE])     + bf2f(al[base + PLANE]))     * w;
    s[2] += (bf2f(ah[base + 2 * PLANE]) + bf2f(al[base + 2 * PLANE])) * w;
  }
#pragma unroll
  for (int i = 0; i < 3; ++i)
    for (int o = 32; o >= 1; o >>= 1) s[i] += __shfl_down(s[i], o);
  if ((tid & 63) == 0)
#pragma unroll
    for (int i = 0; i < 3; ++i) red[i][tid >> 6] = s[i];
  __syncthreads();
  if (tid < 3) {
    const float t = red[tid][0] + red[tid][1] + red[tid][2] + red[tid][3];
    out[b * 3 + tid] = t * 0.03125f;
  }
}

extern "C" void kernel_launch(void* const* d_in, const int* in_sizes, int n_in,
                              void* d_out, int out_size, void* d_ws, size_t ws_size,
                              hipStream_t stream) {
  const float* x    = (const float*)d_in[0];
  const float* w1   = (const float*)d_in[1];
  const float* W    = (const float*)d_in[2];
  const float* bnw  = (const float*)d_in[3];
  const float* wout = (const float*)d_in[4];
  float* out = (float*)d_out;

  char* ws = (char*)d_ws;
  float*          var = (float*)ws;                         // 6*1024 f32 (32 KB resv)
  float*          pre = (float*)(ws + 32768);               // 3072*1024 f32 (12 MB)
  unsigned short* ah  = (unsigned short*)(ws + 12615680);   // 3*1M bf16 (6 MB)
  unsigned short* al  = (unsigned short*)(ws + 18907136);   // 3*1M bf16 (6 MB)
  unsigned short* wh  = (unsigned short*)(ws + 25198592);   // 5*1M bf16 (10 MB)
  unsigned short* wl  = (unsigned short*)(ws + 35684352);   // 5*1M bf16 (10 MB)

  hipMemsetAsync(var, 0, 6 * 1024 * sizeof(float), stream);
  convert_w<<<dim3(16, 16, 5), 256, 0, stream>>>(W, wh, wl);
  layer0<<<4096, 256, 0, stream>>>(x, w1, pre);
  colsumsq<<<dim3(24, 4), 256, 0, stream>>>(pre, var);
  act_kernel<<<1024, 256, 0, stream>>>(pre, var, bnw, ah, al);
  for (int b = 0; b < 5; ++b) {
    gemm_fused<<<dim3(24, 8), 256, 0, stream>>>(
        ah, al, wh + (size_t)b * PLANE, wl + (size_t)b * PLANE,
        pre, var + (b + 1) * 1024);
    act_kernel<<<1024, 256, 0, stream>>>(pre, var + (b + 1) * 1024,
                                         bnw + (size_t)(b + 1) * 4096, ah, al);
  }
  final_kernel<<<1024, 256, 0, stream>>>(ah, al, wout, out);
}